// Round 4
// baseline (62.020 us; speedup 1.0000x reference)
//
#include <hip/hip_runtime.h>
#include <math.h>

#define H 1024
#define T 4096
#define B 16
#define TCHUNK 8

typedef float f4 __attribute__((ext_vector_type(4)));

// Kernel 1: v[b,h] = sum_d dec[d,b] * W[d,h]   (v = dec^T @ W, 16x1024)
// Grid: 256 blocks = 16 b x 16 h-tiles (64 h each). Block: 256 thr =
// 16 dc (d-split) x 16 h4 (float4 h-groups); LDS tree-reduce over dc.
__global__ void __launch_bounds__(256) proj_vec_kernel(
    const float* __restrict__ dec, const float* __restrict__ W,
    float* __restrict__ v)
{
    int b     = blockIdx.x >> 4;
    int htile = blockIdx.x & 15;
    int h4    = threadIdx.x & 15;
    int dc    = threadIdx.x >> 4;
    int h4base = htile * 16;

    const f4* Wp = (const f4*)W;
    f4 acc = {0.f, 0.f, 0.f, 0.f};
    int d0 = dc * 64;
    #pragma unroll 8
    for (int i = 0; i < 64; ++i) {
        int d = d0 + i;
        float s = dec[d * B + b];
        f4 w = Wp[d * (H / 4) + h4base + h4];
        acc += s * w;
    }

    __shared__ f4 red[256];
    red[threadIdx.x] = acc;
    __syncthreads();
    #pragma unroll
    for (int s = 8; s > 0; s >>= 1) {
        if (dc < s) {
            f4 m = red[dc * 16 + h4] + red[(dc + s) * 16 + h4];
            red[dc * 16 + h4] = m;
        }
        __syncthreads();
    }
    if (dc == 0) {
        ((f4*)(v + b * H))[h4base + h4] = red[h4];
    }
}

// Kernel 2: scores[b,t] = dot(v[b,:], enc[t,b,:]).
// One wave per (b, t-chunk of 8). v[b,:] loaded ONCE into 16 VGPRs, then
// 8 enc rows (32 KiB) streamed nontemporally against register-held v.
// Halves VMEM instruction count vs per-row v reloads; 8 independent row
// loads give deep MLP; reduction amortized over 32 KiB.
__global__ void __launch_bounds__(256) scores_kernel(
    const float* __restrict__ v, const float* __restrict__ enc,
    float* __restrict__ scores)
{
    int wave = (int)((blockIdx.x * 256u + threadIdx.x) >> 6);  // 0..8191
    int lane = threadIdx.x & 63;
    int b  = wave & (B - 1);
    int t0 = (wave >> 4) * TCHUNK;

    const f4* vp = (const f4*)(v + b * H);
    f4 vr[4];
    #pragma unroll
    for (int i = 0; i < 4; ++i) vr[i] = vp[lane + i * 64];

    // enc in f4 units: idx = (t*B + b)*(H/4) + lane + i*64
    const f4* ep = (const f4*)enc + ((size_t)t0 * B + b) * (H / 4) + lane;
    const int trow = B * (H / 4);   // f4 stride between consecutive t

    float acc[TCHUNK];
    #pragma unroll
    for (int j = 0; j < TCHUNK; ++j) {
        f4 s = {0.f, 0.f, 0.f, 0.f};
        #pragma unroll
        for (int i = 0; i < 4; ++i) {
            f4 e = __builtin_nontemporal_load(ep + (size_t)j * trow + i * 64);
            s += e * vr[i];
        }
        acc[j] = s.x + s.y + s.z + s.w;
    }

    #pragma unroll
    for (int off = 32; off > 0; off >>= 1) {
        #pragma unroll
        for (int j = 0; j < TCHUNK; ++j)
            acc[j] += __shfl_down(acc[j], off);
    }
    if (lane == 0) {
        f4 r0 = {acc[0], acc[1], acc[2], acc[3]};
        f4 r1 = {acc[4], acc[5], acc[6], acc[7]};
        f4* sp = (f4*)(scores + (size_t)b * T + t0);
        sp[0] = r0;
        sp[1] = r1;
    }
}

// Kernel 3: row softmax, one block (256 threads = 4 waves) per b.
__global__ void __launch_bounds__(256) softmax_kernel(
    const float* __restrict__ scores, float* __restrict__ out)
{
    int b = blockIdx.x;
    int tid = threadIdx.x;
    __shared__ float red[8];
    const f4* rp = (const f4*)(scores + (size_t)b * T);
    f4 vals[4];
    float m = -INFINITY;
    #pragma unroll
    for (int i = 0; i < 4; ++i) {
        vals[i] = rp[tid + i * 256];
        m = fmaxf(m, fmaxf(fmaxf(vals[i].x, vals[i].y), fmaxf(vals[i].z, vals[i].w)));
    }
    #pragma unroll
    for (int off = 32; off > 0; off >>= 1)
        m = fmaxf(m, __shfl_down(m, off));
    if ((tid & 63) == 0) red[tid >> 6] = m;
    __syncthreads();
    m = fmaxf(fmaxf(red[0], red[1]), fmaxf(red[2], red[3]));

    float s = 0.f;
    #pragma unroll
    for (int i = 0; i < 4; ++i) {
        vals[i].x = __expf(vals[i].x - m);
        vals[i].y = __expf(vals[i].y - m);
        vals[i].z = __expf(vals[i].z - m);
        vals[i].w = __expf(vals[i].w - m);
        s += vals[i].x + vals[i].y + vals[i].z + vals[i].w;
    }
    #pragma unroll
    for (int off = 32; off > 0; off >>= 1)
        s += __shfl_down(s, off);
    if ((tid & 63) == 0) red[4 + (tid >> 6)] = s;
    __syncthreads();
    float inv = 1.f / (red[4] + red[5] + red[6] + red[7]);

    f4* op = (f4*)(out + (size_t)b * T);
    #pragma unroll
    for (int i = 0; i < 4; ++i) {
        f4 r = vals[i] * inv;
        op[tid + i * 256] = r;
    }
}

extern "C" void kernel_launch(void* const* d_in, const int* in_sizes, int n_in,
                              void* d_out, int out_size, void* d_ws, size_t ws_size,
                              hipStream_t stream)
{
    const float* dec = (const float*)d_in[0];   // [H, B]
    const float* enc = (const float*)d_in[1];   // [T, B, H]
    const float* W   = (const float*)d_in[2];   // [H, H]
    float* out = (float*)d_out;                 // [B, T]

    float* v      = (float*)d_ws;               // B*H floats  (64 KiB)
    float* scores = v + B * H;                  // B*T floats  (256 KiB)

    proj_vec_kernel<<<256, 256, 0, stream>>>(dec, W, v);
    scores_kernel<<<(T * B / TCHUNK) / 4, 256, 0, stream>>>(v, enc, scores);
    softmax_kernel<<<B, 256, 0, stream>>>(scores, out);
}